// Round 8
// baseline (34463.556 us; speedup 1.0000x reference)
//
#include <hip/hip_runtime.h>

#define NTOK 32768   // input rows
#define KEMB 8192    // embedding codes
#define DIM  256     // feature dim

// ---------------------------------------------------------------------------
// numpy-pairwise fp32 sum of squares of a 256-element contiguous row.
// numpy pairwise_sum(a,256) = pw(a,128) + pw(a+128,128); each 128-block uses
// 8 accumulators r_j = a[j] + a[j+8] + ... + a[j+120] (16 sequential fp32
// adds of fp32-rounded squares), combined ((r0+r1)+(r2+r3))+((r4+r5)+(r6+r7)).
// One 16-lane group per row: lane l -> j = l&7, half = l>>3. The shfl_xor
// 1,2,4 butterfly reproduces the exact 8-way combine tree; xor 8 adds the
// two 128-blocks. All adds via __fadd_rn (unfusable, IEEE fp32).
// ---------------------------------------------------------------------------
__global__ __launch_bounds__(256) void rowsq_np(const float* __restrict__ src,
                                                float* __restrict__ dst,
                                                int nrows) {
  int g = (blockIdx.x * 256 + threadIdx.x) >> 4;   // row id
  if (g >= nrows) return;
  int l = threadIdx.x & 15;
  int j = l & 7, half = l >> 3;
  const float* row = src + (size_t)g * DIM + half * 128 + j;
  float s = 0.f;
  #pragma unroll
  for (int i = 0; i < 16; ++i) {
    float v = row[8 * i];
    s = __fadd_rn(s, __fmul_rn(v, v));   // fp32 square then fp32 add, unfused
  }
  s = __fadd_rn(s, __shfl_xor(s, 1));    // (r0+r1), (r2+r3), ...
  s = __fadd_rn(s, __shfl_xor(s, 2));    // ((r0+r1)+(r2+r3)), ...
  s = __fadd_rn(s, __shfl_xor(s, 4));    // full 8-way block sum
  s = __fadd_rn(s, __shfl_xor(s, 8));    // left128 + right128
  if (l == 0) dst[g] = s;
}

// ---------------------------------------------------------------------------
// Exhaustive argmin under numpy-float32-faithful semantics:
//   d[n,k] = fp32( fp32(A[n] + B[k]) - fp32(2 * C32[n,k]) )
// where A,B are numpy-pairwise fp32 row sums (above), C32 = fp32 rounding of
// the exact (fp64) dot x_n . e_k  (matches BLAS sgemm to ~1e-9, far below the
// ulp(256)=3e-5 grid that creates the ties). Argmin: strict <, ascending k
// == numpy first-min tie semantics. 4 waves/block, 2 rows/wave.
// ---------------------------------------------------------------------------
__global__ __launch_bounds__(256) void exhaustive_np(
    const float* __restrict__ x,
    const float* __restrict__ e,
    const float* __restrict__ An,
    const float* __restrict__ Bk,
    float* __restrict__ out,
    double* __restrict__ partials) {
  __shared__ __align__(16) float4 Ech[32][64];  // 32 codes x 256 f32 = 32 KB
  __shared__ float Bs[32];
  __shared__ double wsum[8];

  const int tid = threadIdx.x;
  const int lane = tid & 63, wid = tid >> 6;
  const int n0 = blockIdx.x * 8 + wid * 2;      // this wave's rows: n0, n0+1

  float4 xa = ((const float4*)x)[(size_t)n0 * 64 + lane];
  float4 xb = ((const float4*)x)[(size_t)(n0 + 1) * 64 + lane];
  double xd0[4] = {xa.x, xa.y, xa.z, xa.w};
  double xd1[4] = {xb.x, xb.y, xb.z, xb.w};
  const float A0 = An[n0], A1 = An[n0 + 1];

  float bd0 = INFINITY, bd1 = INFINITY;
  int bi0 = 0, bi1 = 0;

  for (int c = 0; c < KEMB / 32; ++c) {
    __syncthreads();
    #pragma unroll
    for (int t = 0; t < 8; ++t) {
      int idx = t * 256 + tid;                  // 0..2047
      int row = idx >> 6, col = idx & 63;
      Ech[row][col] = ((const float4*)e)[(size_t)(c * 32 + row) * 64 + col];
    }
    if (tid < 32) Bs[tid] = Bk[c * 32 + tid];
    __syncthreads();

    for (int kk = 0; kk < 32; ++kk) {
      float4 ev = Ech[kk][lane];
      double e0 = ev.x, e1 = ev.y, e2 = ev.z, e3 = ev.w;
      double d0 = e0 * xd0[0] + e1 * xd0[1] + e2 * xd0[2] + e3 * xd0[3];
      double d1 = e0 * xd1[0] + e1 * xd1[1] + e2 * xd1[2] + e3 * xd1[3];
      #pragma unroll
      for (int sh = 1; sh < 64; sh <<= 1) {
        d0 += __shfl_xor(d0, sh);
        d1 += __shfl_xor(d1, sh);
      }
      int k = c * 32 + kk;
      // numpy fp32 pipeline: t1 = A + B; t2 = 2*C32; d = t1 - t2 (all fp32)
      float c320 = (float)d0;
      float c321 = (float)d1;
      float dd0 = __fsub_rn(__fadd_rn(A0, Bs[kk]), __fmul_rn(2.0f, c320));
      float dd1 = __fsub_rn(__fadd_rn(A1, Bs[kk]), __fmul_rn(2.0f, c321));
      if (dd0 < bd0) { bd0 = dd0; bi0 = k; }    // strict < : first-min ties
      if (dd1 < bd1) { bd1 = dd1; bi1 = k; }
    }
  }

  // ---- outputs for the wave's 2 rows (original-precision data) ----
  #pragma unroll
  for (int r = 0; r < 2; ++r) {
    int n = n0 + r;
    int bi = r ? bi1 : bi0;
    float4 q = ((const float4*)e)[(size_t)bi * 64 + lane];
    ((float4*)out)[(size_t)n * 64 + lane] = q;   // quantized_st == quantized
    float4 xo = r ? xb : xa;
    double a0 = (double)q.x - (double)xo.x;
    double a1 = (double)q.y - (double)xo.y;
    double a2 = (double)q.z - (double)xo.z;
    double a3 = (double)q.w - (double)xo.w;
    double l = a0 * a0 + a1 * a1 + a2 * a2 + a3 * a3;
    #pragma unroll
    for (int sh = 1; sh < 64; sh <<= 1) l += __shfl_xor(l, sh);
    if (lane == 0) {
      wsum[wid * 2 + r] = l;
      out[(size_t)NTOK * DIM + 1 + n] = (float)bi;   // indices region
    }
  }
  __syncthreads();
  if (tid == 0) {
    double s = 0;
    #pragma unroll
    for (int i = 0; i < 8; ++i) s += wsum[i];
    partials[blockIdx.x] = s;
  }
}

// ---------------- finalize: deterministic loss reduction ----------------
__global__ __launch_bounds__(256) void finalize(const double* __restrict__ partials,
                                                float* __restrict__ out) {
  __shared__ double sd[256];
  double s = 0;
  for (int i = threadIdx.x; i < NTOK / 8; i += 256) s += partials[i];
  sd[threadIdx.x] = s;
  __syncthreads();
  for (int st = 128; st > 0; st >>= 1) {
    if (threadIdx.x < st) sd[threadIdx.x] += sd[threadIdx.x + st];
    __syncthreads();
  }
  if (threadIdx.x == 0)
    out[(size_t)NTOK * DIM] = (float)(1.25 * sd[0] / ((double)NTOK * (double)DIM));
}

extern "C" void kernel_launch(void* const* d_in, const int* in_sizes, int n_in,
                              void* d_out, int out_size, void* d_ws, size_t ws_size,
                              hipStream_t stream) {
  const float* x = (const float*)d_in[0];   // [32768, 256]
  const float* e = (const float*)d_in[1];   // [8192, 256]
  float* out = (float*)d_out;

  // workspace layout (tiny)
  char* w = (char*)d_ws;
  float* An        = (float*)(w + 0);           // 131,072 B
  float* Bk        = (float*)(w + 131072);      //  32,768 B
  double* partials = (double*)(w + 163840);     //  32,768 B

  rowsq_np<<<NTOK / 16, 256, 0, stream>>>(x, An, NTOK);
  rowsq_np<<<KEMB / 16, 256, 0, stream>>>(e, Bk, KEMB);

  exhaustive_np<<<NTOK / 8, 256, 0, stream>>>(x, e, An, Bk, out, partials);
  finalize<<<1, 256, 0, stream>>>(partials, out);
}

// Round 9
// 2173.537 us; speedup vs baseline: 15.8560x; 15.8560x over previous
//
#include <hip/hip_runtime.h>
#include <hip/hip_bf16.h>

#define NTOK 32768   // input rows
#define KEMB 8192    // embedding codes
#define DIM  256     // feature dim
#define EPSM 5e-4f   // gate margin: worst-case |approx - np_exact| ~ 1.1e-4

typedef __attribute__((ext_vector_type(8))) short bf16x8;
typedef __attribute__((ext_vector_type(4))) float f32x4;
typedef __attribute__((ext_vector_type(8))) unsigned short ushort8;

typedef __attribute__((address_space(3))) void as3_void;
typedef __attribute__((address_space(1))) const void as1_cvoid;

__device__ __forceinline__ void gload_lds16(const void* g, void* l) {
  __builtin_amdgcn_global_load_lds((as1_cvoid*)g, (as3_void*)l, 16, 0, 0);
}

__device__ __forceinline__ unsigned short f2bf(float f) {
  unsigned int u = __float_as_uint(f);
  unsigned int r = (u + 0x7FFFu + ((u >> 16) & 1u)) >> 16;
  return (unsigned short)r;
}

// ---------------- prep: fp32 -> bf16 copies ----------------
__global__ __launch_bounds__(256) void cast_bf16_k(const float* __restrict__ src,
                                                   unsigned short* __restrict__ dst,
                                                   int n8) {
  int i = blockIdx.x * 256 + threadIdx.x;
  if (i >= n8) return;
  const float4* s4 = (const float4*)src;
  float4 a = s4[2 * i], b = s4[2 * i + 1];
  ushort8 r;
  r[0] = f2bf(a.x); r[1] = f2bf(a.y); r[2] = f2bf(a.z); r[3] = f2bf(a.w);
  r[4] = f2bf(b.x); r[5] = f2bf(b.y); r[6] = f2bf(b.z); r[7] = f2bf(b.w);
  ((ushort8*)dst)[i] = r;
}

// ---------------- numpy-pairwise fp32 row sum of squares (validated r8) ------
__global__ __launch_bounds__(256) void rowsq_np(const float* __restrict__ src,
                                                float* __restrict__ dst,
                                                int nrows) {
  int g = (blockIdx.x * 256 + threadIdx.x) >> 4;   // row id
  if (g >= nrows) return;
  int l = threadIdx.x & 15;
  int j = l & 7, half = l >> 3;
  const float* row = src + (size_t)g * DIM + half * 128 + j;
  float s = 0.f;
  #pragma unroll
  for (int i = 0; i < 16; ++i) {
    float v = row[8 * i];
    s = __fadd_rn(s, __fmul_rn(v, v));
  }
  s = __fadd_rn(s, __shfl_xor(s, 1));
  s = __fadd_rn(s, __shfl_xor(s, 2));
  s = __fadd_rn(s, __shfl_xor(s, 4));
  s = __fadd_rn(s, __shfl_xor(s, 8));
  if (l == 0) dst[g] = s;
}

// ---------------- main: bf16 MFMA approx scores + per-block column min -------
// Transposed GEMM: C[k_local, n_local] = sum_d E[k,d] * X[n,d];
// s_hat = Bk[k] - 2*C. Tile 128(k) x 128(n), 4 chunks of BK=64 over D=256.
// Output: top1[kb][n] = min over the block's 128 codes (gate input only).
__global__ __launch_bounds__(256) void score_top1(
    const unsigned short* __restrict__ eb,
    const unsigned short* __restrict__ xb,
    const float* __restrict__ Bk,
    float* __restrict__ top1out) {
  __shared__ __align__(16) short Es[128 * 64];
  __shared__ __align__(16) short Xs[128 * 64];
  __shared__ float bks[128];
  __shared__ float t1lds[128][2];

  const int tid = threadIdx.x;
  const int kb = blockIdx.x, nb = blockIdx.y;
  const int kbase = kb * 128, nbase = nb * 128;
  const int lane = tid & 63;
  const int wid = tid >> 6;
  const int wr = wid >> 1, wc = wid & 1;
  const int l15 = lane & 15, lhi = lane >> 4;

  if (tid < 128) bks[tid] = Bk[kbase + tid];

  f32x4 acc[4][4];
  #pragma unroll
  for (int i = 0; i < 4; ++i)
    #pragma unroll
    for (int j = 0; j < 4; ++j) acc[i][j] = (f32x4){0.f, 0.f, 0.f, 0.f};

  #pragma unroll
  for (int kc = 0; kc < 4; ++kc) {
    __syncthreads();
    #pragma unroll
    for (int it = 0; it < 4; ++it) {
      int c = it * 256 + tid;           // 0..1023 16B-chunks
      int row = c >> 3, col = (c & 7) * 8;
      gload_lds16(eb + (size_t)(kbase + row) * DIM + kc * 64 + col, &Es[c * 8]);
      gload_lds16(xb + (size_t)(nbase + row) * DIM + kc * 64 + col, &Xs[c * 8]);
    }
    __syncthreads();  // drains vmcnt(0): staged data visible
    #pragma unroll
    for (int kk = 0; kk < 2; ++kk) {
      const int dofs = kk * 32 + lhi * 8;
      bf16x8 af[4], bfv[4];
      #pragma unroll
      for (int am = 0; am < 4; ++am)
        af[am] = *(const bf16x8*)(&Es[(64 * wr + 16 * am + l15) * 64 + dofs]);
      #pragma unroll
      for (int bn = 0; bn < 4; ++bn)
        bfv[bn] = *(const bf16x8*)(&Xs[(64 * wc + 16 * bn + l15) * 64 + dofs]);
      #pragma unroll
      for (int am = 0; am < 4; ++am)
        #pragma unroll
        for (int bn = 0; bn < 4; ++bn)
          acc[am][bn] = __builtin_amdgcn_mfma_f32_16x16x32_bf16(
              af[am], bfv[bn], acc[am][bn], 0, 0, 0);
    }
  }

  // epilogue: per column, min of s_hat over this block's 128 codes.
  // C/D layout: col = lane&15, row(within 16) = lhi*4 + r.
  float bv[16];
  const int rb = 64 * wr + lhi * 4;
  #pragma unroll
  for (int am = 0; am < 4; ++am)
    #pragma unroll
    for (int r = 0; r < 4; ++r) bv[am * 4 + r] = bks[rb + 16 * am + r];

  #pragma unroll
  for (int bn = 0; bn < 4; ++bn) {
    float v1 = INFINITY;
    #pragma unroll
    for (int am = 0; am < 4; ++am)
      #pragma unroll
      for (int r = 0; r < 4; ++r)
        v1 = fminf(v1, fmaf(-2.f, acc[am][bn][r], bv[am * 4 + r]));
    v1 = fminf(v1, __shfl_xor(v1, 16));
    v1 = fminf(v1, __shfl_xor(v1, 32));
    if (lane < 16) t1lds[64 * wc + 16 * bn + lane][wr] = v1;
  }
  __syncthreads();
  if (tid < 128)
    top1out[(size_t)kb * NTOK + nbase + tid] = fminf(t1lds[tid][0], t1lds[tid][1]);
}

// ---------------- refine: np-faithful argmin over gated blocks ----------------
// dd = fp32( fp32(A[n]+B[k]) - fp32(2 * fp32(exact_dot)) )  -- bit-identical
// arithmetic to the validated exhaustive_np kernel; scanned blocks = all with
// v1 <= min(v1) + EPSM (provably contains the np winner). Ascending order ->
// numpy first-min tie semantics.
__global__ __launch_bounds__(256) void refine_np(
    const float* __restrict__ top1,
    const float* __restrict__ x,
    const float* __restrict__ e,
    const float* __restrict__ An,
    const float* __restrict__ Bk,
    float* __restrict__ out,
    double* __restrict__ partials) {
  __shared__ double wsum[4];
  const int tid = threadIdx.x;
  const int lane = tid & 63, wid = tid >> 6;
  const int n = blockIdx.x * 4 + wid;  // one wave per row

  float v1 = top1[(size_t)lane * NTOK + n];  // lane = kblock id
  float m = v1;
  #pragma unroll
  for (int s = 1; s < 64; s <<= 1) m = fminf(m, __shfl_xor(m, s));
  unsigned long long fb = __ballot(v1 <= m + EPSM);  // >=1 block always

  float4 xv = ((const float4*)x)[(size_t)n * 64 + lane];
  double xd0 = xv.x, xd1 = xv.y, xd2 = xv.z, xd3 = xv.w;
  const float A0 = An[n];

  float bd = INFINITY; int bi = 0;
  while (fb) {
    int b = __ffsll((unsigned long long)fb) - 1;
    fb &= fb - 1;
    for (int kk = 0; kk < 128; ++kk) {
      int kidx = b * 128 + kk;   // ascending -> first-min semantics
      float4 ev = ((const float4*)e)[(size_t)kidx * 64 + lane];
      double d = ev.x * xd0 + ev.y * xd1 + ev.z * xd2 + ev.w * xd3;
      #pragma unroll
      for (int sh = 1; sh < 64; sh <<= 1) d += __shfl_xor(d, sh);
      float dd = __fsub_rn(__fadd_rn(A0, Bk[kidx]), __fmul_rn(2.0f, (float)d));
      if (dd < bd) { bd = dd; bi = kidx; }
    }
  }

  // outputs
  float4 q = ((const float4*)e)[(size_t)bi * 64 + lane];
  ((float4*)out)[(size_t)n * 64 + lane] = q;  // quantized_st == quantized
  double a0 = (double)q.x - (double)xv.x;
  double a1 = (double)q.y - (double)xv.y;
  double a2 = (double)q.z - (double)xv.z;
  double a3 = (double)q.w - (double)xv.w;
  double l = a0 * a0 + a1 * a1 + a2 * a2 + a3 * a3;
  #pragma unroll
  for (int sh = 1; sh < 64; sh <<= 1) l += __shfl_xor(l, sh);
  if (lane == 0) {
    wsum[wid] = l;
    out[(size_t)NTOK * DIM + 1 + n] = (float)bi;  // indices region
  }
  __syncthreads();
  if (tid == 0) partials[blockIdx.x] = wsum[0] + wsum[1] + wsum[2] + wsum[3];
}

// ---------------- finalize: deterministic loss reduction ----------------
__global__ __launch_bounds__(256) void finalize(const double* __restrict__ partials,
                                                float* __restrict__ out) {
  __shared__ double sd[256];
  double s = 0;
  for (int i = threadIdx.x; i < NTOK / 4; i += 256) s += partials[i];
  sd[threadIdx.x] = s;
  __syncthreads();
  for (int st = 128; st > 0; st >>= 1) {
    if (threadIdx.x < st) sd[threadIdx.x] += sd[threadIdx.x + st];
    __syncthreads();
  }
  if (threadIdx.x == 0)
    out[(size_t)NTOK * DIM] = (float)(1.25 * sd[0] / ((double)NTOK * (double)DIM));
}

extern "C" void kernel_launch(void* const* d_in, const int* in_sizes, int n_in,
                              void* d_out, int out_size, void* d_ws, size_t ws_size,
                              hipStream_t stream) {
  const float* x = (const float*)d_in[0];   // [32768, 256]
  const float* e = (const float*)d_in[1];   // [8192, 256]
  float* out = (float*)d_out;

  // workspace layout (~29.6 MB)
  char* w = (char*)d_ws;
  unsigned short* xb = (unsigned short*)(w + 0);            // 16,777,216 B
  unsigned short* eb = (unsigned short*)(w + 16777216);     //  4,194,304 B
  float* An        = (float*)(w + 20971520);                //    131,072 B
  float* Bk        = (float*)(w + 21102592);                //     32,768 B
  float* top1      = (float*)(w + 21135360);                //  8,388,608 B
  double* partials = (double*)(w + 29523968);               //     65,536 B

  cast_bf16_k<<<(NTOK * DIM / 8 + 255) / 256, 256, 0, stream>>>(x, xb, NTOK * DIM / 8);
  cast_bf16_k<<<(KEMB * DIM / 8 + 255) / 256, 256, 0, stream>>>(e, eb, KEMB * DIM / 8);
  rowsq_np<<<NTOK / 16, 256, 0, stream>>>(x, An, NTOK);
  rowsq_np<<<KEMB / 16, 256, 0, stream>>>(e, Bk, KEMB);

  dim3 g2(KEMB / 128, NTOK / 128);  // (64, 256)
  score_top1<<<g2, 256, 0, stream>>>(eb, xb, Bk, top1);

  refine_np<<<NTOK / 4, 256, 0, stream>>>(top1, x, e, An, Bk, out, partials);
  finalize<<<1, 256, 0, stream>>>(partials, out);
}

// Round 10
// 389.398 us; speedup vs baseline: 88.5047x; 5.5818x over previous
//
#include <hip/hip_runtime.h>
#include <hip/hip_bf16.h>

#define NTOK 32768   // input rows
#define KEMB 8192    // embedding codes
#define DIM  256     // feature dim
#define EPSM 1e-3f   // gate margin: worst-case |s_hat - np_dd| + slack (~3x)

typedef __attribute__((ext_vector_type(8))) short bf16x8;
typedef __attribute__((ext_vector_type(4))) float f32x4;
typedef __attribute__((ext_vector_type(8))) unsigned short ushort8;

typedef __attribute__((address_space(3))) void as3_void;
typedef __attribute__((address_space(1))) const void as1_cvoid;

__device__ __forceinline__ void gload_lds16(const void* g, void* l) {
  __builtin_amdgcn_global_load_lds((as1_cvoid*)g, (as3_void*)l, 16, 0, 0);
}

__device__ __forceinline__ unsigned short f2bf(float f) {
  unsigned int u = __float_as_uint(f);
  unsigned int r = (u + 0x7FFFu + ((u >> 16) & 1u)) >> 16;
  return (unsigned short)r;
}

// ---------------- prep: fp32 -> bf16 copies ----------------
__global__ __launch_bounds__(256) void cast_bf16_k(const float* __restrict__ src,
                                                   unsigned short* __restrict__ dst,
                                                   int n8) {
  int i = blockIdx.x * 256 + threadIdx.x;
  if (i >= n8) return;
  const float4* s4 = (const float4*)src;
  float4 a = s4[2 * i], b = s4[2 * i + 1];
  ushort8 r;
  r[0] = f2bf(a.x); r[1] = f2bf(a.y); r[2] = f2bf(a.z); r[3] = f2bf(a.w);
  r[4] = f2bf(b.x); r[5] = f2bf(b.y); r[6] = f2bf(b.z); r[7] = f2bf(b.w);
  ((ushort8*)dst)[i] = r;
}

// ---------------- numpy-pairwise fp32 row sum of squares (validated r8) ------
__global__ __launch_bounds__(256) void rowsq_np(const float* __restrict__ src,
                                                float* __restrict__ dst,
                                                int nrows) {
  int g = (blockIdx.x * 256 + threadIdx.x) >> 4;   // row id
  if (g >= nrows) return;
  int l = threadIdx.x & 15;
  int j = l & 7, half = l >> 3;
  const float* row = src + (size_t)g * DIM + half * 128 + j;
  float s = 0.f;
  #pragma unroll
  for (int i = 0; i < 16; ++i) {
    float v = row[8 * i];
    s = __fadd_rn(s, __fmul_rn(v, v));
  }
  s = __fadd_rn(s, __shfl_xor(s, 1));
  s = __fadd_rn(s, __shfl_xor(s, 2));
  s = __fadd_rn(s, __shfl_xor(s, 4));
  s = __fadd_rn(s, __shfl_xor(s, 8));
  if (l == 0) dst[g] = s;
}

// ---------------- main: bf16 MFMA approx scores + per-block top-2 (+v3) ------
// Transposed GEMM: C[k_local, n_local] = sum_d E[k,d] * X[n,d];
// s_hat = Bk[k] - 2*C. Tile 128(k) x 128(n), 4 chunks of BK=64 over D=256.
__global__ __launch_bounds__(256) void score_top2(
    const unsigned short* __restrict__ eb,
    const unsigned short* __restrict__ xb,
    const float* __restrict__ Bk,
    float4* __restrict__ top2out,
    float* __restrict__ v3out) {
  __shared__ __align__(16) short Es[128 * 64];
  __shared__ __align__(16) short Xs[128 * 64];
  __shared__ float bks[128];
  __shared__ float4 t2lds[256];   // [col 0..127][wr 0..1]
  __shared__ float v3lds[256];

  const int tid = threadIdx.x;
  const int kb = blockIdx.x, nb = blockIdx.y;
  const int kbase = kb * 128, nbase = nb * 128;
  const int lane = tid & 63;
  const int wid = tid >> 6;
  const int wr = wid >> 1, wc = wid & 1;
  const int l15 = lane & 15, lhi = lane >> 4;

  if (tid < 128) bks[tid] = Bk[kbase + tid];

  f32x4 acc[4][4];
  #pragma unroll
  for (int i = 0; i < 4; ++i)
    #pragma unroll
    for (int j = 0; j < 4; ++j) acc[i][j] = (f32x4){0.f, 0.f, 0.f, 0.f};

  #pragma unroll
  for (int kc = 0; kc < 4; ++kc) {
    __syncthreads();
    #pragma unroll
    for (int it = 0; it < 4; ++it) {
      int c = it * 256 + tid;           // 0..1023 16B-chunks
      int row = c >> 3, col = (c & 7) * 8;
      gload_lds16(eb + (size_t)(kbase + row) * DIM + kc * 64 + col, &Es[c * 8]);
      gload_lds16(xb + (size_t)(nbase + row) * DIM + kc * 64 + col, &Xs[c * 8]);
    }
    __syncthreads();  // drains vmcnt(0): staged data visible
    #pragma unroll
    for (int kk = 0; kk < 2; ++kk) {
      const int dofs = kk * 32 + lhi * 8;
      bf16x8 af[4], bfv[4];
      #pragma unroll
      for (int am = 0; am < 4; ++am)
        af[am] = *(const bf16x8*)(&Es[(64 * wr + 16 * am + l15) * 64 + dofs]);
      #pragma unroll
      for (int bn = 0; bn < 4; ++bn)
        bfv[bn] = *(const bf16x8*)(&Xs[(64 * wc + 16 * bn + l15) * 64 + dofs]);
      #pragma unroll
      for (int am = 0; am < 4; ++am)
        #pragma unroll
        for (int bn = 0; bn < 4; ++bn)
          acc[am][bn] = __builtin_amdgcn_mfma_f32_16x16x32_bf16(
              af[am], bfv[bn], acc[am][bn], 0, 0, 0);
    }
  }

  // ---- epilogue: per output column (n), top-3 values / top-2 indices ----
  float bv[16];
  const int rb = 64 * wr + lhi * 4;
  #pragma unroll
  for (int am = 0; am < 4; ++am)
    #pragma unroll
    for (int r = 0; r < 4; ++r) bv[am * 4 + r] = bks[rb + 16 * am + r];

  #pragma unroll
  for (int bn = 0; bn < 4; ++bn) {
    float v1 = INFINITY, v2 = INFINITY, v3 = INFINITY;
    int i1 = 0, i2 = 0;
    #pragma unroll
    for (int am = 0; am < 4; ++am) {
      #pragma unroll
      for (int r = 0; r < 4; ++r) {
        float sc = fmaf(-2.f, acc[am][bn][r], bv[am * 4 + r]);
        int kidx = kbase + rb + 16 * am + r;
        bool lt1 = sc < v1;
        bool lt2 = sc < v2;
        bool lt3 = sc < v3;
        float nv3 = lt2 ? v2 : (lt3 ? sc : v3);
        float nv2 = lt1 ? v1 : (lt2 ? sc : v2);
        int ni2 = lt1 ? i1 : (lt2 ? kidx : i2);
        v1 = lt1 ? sc : v1;
        i1 = lt1 ? kidx : i1;
        v2 = nv2; i2 = ni2; v3 = nv3;
      }
    }
    // merge across the 4 lane-groups (rows interleaved by lane>>4)
    #pragma unroll
    for (int mm = 16; mm <= 32; mm <<= 1) {
      float ov1 = __shfl_xor(v1, mm); int oi1 = __shfl_xor(i1, mm);
      float ov2 = __shfl_xor(v2, mm); int oi2 = __shfl_xor(i2, mm);
      float ov3 = __shfl_xor(v3, mm);
      bool t = ov1 < v1;
      float w1 = t ? ov1 : v1;   int j1  = t ? oi1 : i1;
      float l1 = t ? v1  : ov1;  int lj1 = t ? i1  : oi1;
      float ws2 = t ? ov2 : v2;  int wj2 = t ? oi2 : i2;
      float ws3 = t ? ov3 : v3;
      float ls2 = t ? v2  : ov2;
      bool u = ws2 < l1;
      float w2 = u ? ws2 : l1;   int j2 = u ? wj2 : lj1;
      float w3 = u ? fminf(ws3, l1) : fminf(ws2, ls2);
      v1 = w1; i1 = j1; v2 = w2; i2 = j2; v3 = w3;
    }
    if (lane < 16) {
      int col = 64 * wc + 16 * bn + lane;
      t2lds[col * 2 + wr] = make_float4(v1, __int_as_float(i1), v2, __int_as_float(i2));
      v3lds[col * 2 + wr] = v3;
    }
  }
  __syncthreads();
  if (tid < 128) {
    float4 a = t2lds[tid * 2 + 0];
    float4 b = t2lds[tid * 2 + 1];
    float av3 = v3lds[tid * 2 + 0];
    float bv3 = v3lds[tid * 2 + 1];
    bool t = b.x < a.x;
    float w1 = t ? b.x : a.x;   float j1  = t ? b.y : a.y;
    float l1 = t ? a.x : b.x;   float lj1 = t ? a.y : b.y;
    float ws2 = t ? b.z : a.z;  float wj2 = t ? b.w : a.w;
    float ws3 = t ? bv3 : av3;
    float ls2 = t ? a.z : b.z;
    bool u = ws2 < l1;
    float w2 = u ? ws2 : l1;    float j2 = u ? wj2 : lj1;
    float w3 = u ? fminf(ws3, l1) : fminf(ws2, ls2);
    top2out[(size_t)kb * NTOK + nbase + tid] = make_float4(w1, j1, w2, j2);
    v3out[(size_t)kb * NTOK + nbase + tid] = w3;
  }
}

// ---------------- refine2: candidate-parallel np-faithful argmin -------------
// Candidate set per row: {i1,i2 of blocks with v<=lim} + full scan of blocks
// with v3<=lim (provably complete). One lane per candidate dot (fp64, exact);
// dd via the bit-validated np fp32 pipeline; (dd,k) lex-min = np first-min.
__global__ __launch_bounds__(256) void refine2(
    const float4* __restrict__ top2,
    const float* __restrict__ v3arr,
    const float* __restrict__ x,
    const float* __restrict__ e,
    const float* __restrict__ An,
    const float* __restrict__ Bk,
    float* __restrict__ out,
    double* __restrict__ partials) {
  __shared__ float4 xs[4][64];
  __shared__ int cand[4][128];
  __shared__ int fblk[4][64];
  __shared__ double wsum[4];

  const int tid = threadIdx.x;
  const int lane = tid & 63, wid = tid >> 6;
  const int n = blockIdx.x * 4 + wid;   // one wave per row

  float4 xv = ((const float4*)x)[(size_t)n * 64 + lane];
  xs[wid][lane] = xv;

  float4 t = top2[(size_t)lane * NTOK + n];   // lane = kblock id
  float v3v = v3arr[(size_t)lane * NTOK + n];
  float m = t.x;
  #pragma unroll
  for (int s = 1; s < 64; s <<= 1) m = fminf(m, __shfl_xor(m, s));
  float lim = m + EPSM;

  unsigned long long b1 = __ballot(t.x <= lim);
  unsigned long long b2 = __ballot(t.z <= lim);
  unsigned long long b3 = __ballot(v3v <= lim);
  unsigned long long ltm = (1ull << lane) - 1ull;
  int c1 = __popcll(b1);
  int ncand = c1 + __popcll(b2);
  if (t.x <= lim) cand[wid][__popcll(b1 & ltm)] = __float_as_int(t.y);
  if (t.z <= lim) cand[wid][c1 + __popcll(b2 & ltm)] = __float_as_int(t.w);
  int nflag = __popcll(b3);
  if (v3v <= lim) fblk[wid][__popcll(b3 & ltm)] = lane;
  const float A0 = An[n];
  __syncthreads();

  float bd = INFINITY; int bi = 0x7FFFFFFF;
  for (int base = 0; base < ncand; base += 64) {
    int ci = base + lane;
    if (ci < ncand) {
      int k = cand[wid][ci];
      const float4* er = (const float4*)e + (size_t)k * 64;
      double d = 0.0;
      #pragma unroll 8
      for (int j = 0; j < 64; ++j) {
        float4 ev = er[j];
        float4 xf = xs[wid][j];
        d += (double)ev.x * (double)xf.x + (double)ev.y * (double)xf.y
           + (double)ev.z * (double)xf.z + (double)ev.w * (double)xf.w;
      }
      float dd = __fsub_rn(__fadd_rn(A0, Bk[k]), __fmul_rn(2.0f, (float)d));
      if (dd < bd || (dd == bd && k < bi)) { bd = dd; bi = k; }
    }
  }
  // rare exact fallback: blocks whose top-2 is provably insufficient
  for (int f = 0; f < nflag; ++f) {
    int b = fblk[wid][f];
    #pragma unroll
    for (int half = 0; half < 2; ++half) {
      int k = b * 128 + half * 64 + lane;   // all 64 lanes active
      const float4* er = (const float4*)e + (size_t)k * 64;
      double d = 0.0;
      #pragma unroll 4
      for (int j = 0; j < 64; ++j) {
        float4 ev = er[j];
        float4 xf = xs[wid][j];
        d += (double)ev.x * (double)xf.x + (double)ev.y * (double)xf.y
           + (double)ev.z * (double)xf.z + (double)ev.w * (double)xf.w;
      }
      float dd = __fsub_rn(__fadd_rn(A0, Bk[k]), __fmul_rn(2.0f, (float)d));
      if (dd < bd || (dd == bd && k < bi)) { bd = dd; bi = k; }
    }
  }
  // (dd, k) lexicographic min across the wave == numpy first-min
  #pragma unroll
  for (int s = 1; s < 64; s <<= 1) {
    float od = __shfl_xor(bd, s);
    int oi = __shfl_xor(bi, s);
    if (od < bd || (od == bd && oi < bi)) { bd = od; bi = oi; }
  }

  // outputs
  float4 q = ((const float4*)e)[(size_t)bi * 64 + lane];
  ((float4*)out)[(size_t)n * 64 + lane] = q;   // quantized_st == quantized
  double a0 = (double)q.x - (double)xv.x;
  double a1 = (double)q.y - (double)xv.y;
  double a2 = (double)q.z - (double)xv.z;
  double a3 = (double)q.w - (double)xv.w;
  double l = a0 * a0 + a1 * a1 + a2 * a2 + a3 * a3;
  #pragma unroll
  for (int sh = 1; sh < 64; sh <<= 1) l += __shfl_xor(l, sh);
  if (lane == 0) {
    wsum[wid] = l;
    out[(size_t)NTOK * DIM + 1 + n] = (float)bi;   // indices region
  }
  __syncthreads();
  if (tid == 0) partials[blockIdx.x] = wsum[0] + wsum[1] + wsum[2] + wsum[3];
}

// ---------------- finalize: deterministic loss reduction ----------------
__global__ __launch_bounds__(256) void finalize(const double* __restrict__ partials,
                                                float* __restrict__ out) {
  __shared__ double sd[256];
  double s = 0;
  for (int i = threadIdx.x; i < NTOK / 4; i += 256) s += partials[i];
  sd[threadIdx.x] = s;
  __syncthreads();
  for (int st = 128; st > 0; st >>= 1) {
    if (threadIdx.x < st) sd[threadIdx.x] += sd[threadIdx.x + st];
    __syncthreads();
  }
  if (threadIdx.x == 0)
    out[(size_t)NTOK * DIM] = (float)(1.25 * sd[0] / ((double)NTOK * (double)DIM));
}

extern "C" void kernel_launch(void* const* d_in, const int* in_sizes, int n_in,
                              void* d_out, int out_size, void* d_ws, size_t ws_size,
                              hipStream_t stream) {
  const float* x = (const float*)d_in[0];   // [32768, 256]
  const float* e = (const float*)d_in[1];   // [8192, 256]
  float* out = (float*)d_out;

  // workspace layout (~63.1 MB)
  char* w = (char*)d_ws;
  unsigned short* xb = (unsigned short*)(w + 0);            // 16,777,216 B
  unsigned short* eb = (unsigned short*)(w + 16777216);     //  4,194,304 B
  float* An        = (float*)(w + 20971520);                //    131,072 B
  float* Bk        = (float*)(w + 21102592);                //     32,768 B
  float4* top2     = (float4*)(w + 21135360);               // 33,554,432 B
  float* v3arr     = (float*)(w + 54689792);                //  8,388,608 B
  double* partials = (double*)(w + 63078400);               //     65,536 B

  cast_bf16_k<<<(NTOK * DIM / 8 + 255) / 256, 256, 0, stream>>>(x, xb, NTOK * DIM / 8);
  cast_bf16_k<<<(KEMB * DIM / 8 + 255) / 256, 256, 0, stream>>>(e, eb, KEMB * DIM / 8);
  rowsq_np<<<NTOK / 16, 256, 0, stream>>>(x, An, NTOK);
  rowsq_np<<<KEMB / 16, 256, 0, stream>>>(e, Bk, KEMB);

  dim3 g2(KEMB / 128, NTOK / 128);  // (64, 256)
  score_top2<<<g2, 256, 0, stream>>>(eb, xb, Bk, top2, v3arr);

  refine2<<<NTOK / 4, 256, 0, stream>>>(top2, v3arr, x, e, An, Bk, out, partials);
  finalize<<<1, 256, 0, stream>>>(partials, out);
}

// Round 11
// 356.519 us; speedup vs baseline: 96.6668x; 1.0922x over previous
//
#include <hip/hip_runtime.h>
#include <hip/hip_bf16.h>

#define NTOK 32768   // input rows
#define KEMB 8192    // embedding codes
#define DIM  256     // feature dim
#define EPSM 1e-3f   // gate margin: worst-case |s_hat - np_dd| ~1.1e-4 (+6e-8 key trunc)

typedef __attribute__((ext_vector_type(8))) short bf16x8;
typedef __attribute__((ext_vector_type(4))) float f32x4;
typedef __attribute__((ext_vector_type(8))) unsigned short ushort8;

typedef __attribute__((address_space(3))) void as3_void;
typedef __attribute__((address_space(1))) const void as1_cvoid;

__device__ __forceinline__ void gload_lds16(const void* g, void* l) {
  __builtin_amdgcn_global_load_lds((as1_cvoid*)g, (as3_void*)l, 16, 0, 0);
}

__device__ __forceinline__ unsigned short f2bf(float f) {
  unsigned int u = __float_as_uint(f);
  unsigned int r = (u + 0x7FFFu + ((u >> 16) & 1u)) >> 16;
  return (unsigned short)r;
}

__device__ __forceinline__ unsigned umin2(unsigned a, unsigned b) { return a < b ? a : b; }
__device__ __forceinline__ unsigned umax2(unsigned a, unsigned b) { return a > b ? a : b; }

// order-preserving float->uint key; low 7 bits then hold block-local index
__device__ __forceinline__ unsigned f2key(float f) {
  unsigned u = __float_as_uint(f);
  return u ^ ((unsigned)((int)u >> 31) | 0x80000000u);
}
// inverse (index bits stripped)
__device__ __forceinline__ float key2f(unsigned k) {
  unsigned kk = k & 0xFFFFFF80u;
  unsigned m = (unsigned)((int)kk >> 31);
  return __uint_as_float(kk ^ ((m & 0x80000000u) | ~m));
}

// ---------------- prep: fp32 -> bf16 copies ----------------
__global__ __launch_bounds__(256) void cast_bf16_k(const float* __restrict__ src,
                                                   unsigned short* __restrict__ dst,
                                                   int n8) {
  int i = blockIdx.x * 256 + threadIdx.x;
  if (i >= n8) return;
  const float4* s4 = (const float4*)src;
  float4 a = s4[2 * i], b = s4[2 * i + 1];
  ushort8 r;
  r[0] = f2bf(a.x); r[1] = f2bf(a.y); r[2] = f2bf(a.z); r[3] = f2bf(a.w);
  r[4] = f2bf(b.x); r[5] = f2bf(b.y); r[6] = f2bf(b.z); r[7] = f2bf(b.w);
  ((ushort8*)dst)[i] = r;
}

// ---------------- numpy-pairwise fp32 row sum of squares (validated r8) ------
__global__ __launch_bounds__(256) void rowsq_np(const float* __restrict__ src,
                                                float* __restrict__ dst,
                                                int nrows) {
  int g = (blockIdx.x * 256 + threadIdx.x) >> 4;   // row id
  if (g >= nrows) return;
  int l = threadIdx.x & 15;
  int j = l & 7, half = l >> 3;
  const float* row = src + (size_t)g * DIM + half * 128 + j;
  float s = 0.f;
  #pragma unroll
  for (int i = 0; i < 16; ++i) {
    float v = row[8 * i];
    s = __fadd_rn(s, __fmul_rn(v, v));
  }
  s = __fadd_rn(s, __shfl_xor(s, 1));
  s = __fadd_rn(s, __shfl_xor(s, 2));
  s = __fadd_rn(s, __shfl_xor(s, 4));
  s = __fadd_rn(s, __shfl_xor(s, 8));
  if (l == 0) dst[g] = s;
}

// ---------------- main: bf16 MFMA approx scores + per-block top-3 keys -------
// Transposed GEMM: C[k_local, n_local] = sum_d E[k,d] * X[n,d];
// s_hat = Bk[k] - 2*C. Tile 128(k) x 128(n), 4 chunks of BK=64 over D=256.
// LDS XOR-swizzle (T2, rule #21): linear global_load_lds dest + inverse-
// swizzled GLOBAL source + swizzled ds_read. Epilogue: per column, sorted
// top-3 of packed keys (value<<7 | local idx) -> first-min semantics free.
__global__ __launch_bounds__(256) void score_top2(
    const unsigned short* __restrict__ eb,
    const unsigned short* __restrict__ xb,
    const float* __restrict__ Bk,
    uint4* __restrict__ top2out) {
  __shared__ __align__(16) short Es[128 * 64];
  __shared__ __align__(16) short Xs[128 * 64];
  __shared__ float bks[128];
  __shared__ uint4 t2lds[128][2];   // [col][wr] sorted key-triples

  const int tid = threadIdx.x;
  // XCD-chunked decode: each XCD owns 32 contiguous n-panels, nb-inner
  const int bid = blockIdx.x;
  const int xcd = bid & 7;
  const int u = bid >> 3;
  const int nb = xcd * 32 + (u & 31);
  const int kb = u >> 5;
  const int kbase = kb * 128, nbase = nb * 128;
  const int lane = tid & 63;
  const int wid = tid >> 6;
  const int wr = wid >> 1, wc = wid & 1;
  const int l15 = lane & 15, lhi = lane >> 4;

  if (tid < 128) bks[tid] = Bk[kbase + tid];

  f32x4 acc[4][4];
  #pragma unroll
  for (int i = 0; i < 4; ++i)
    #pragma unroll
    for (int j = 0; j < 4; ++j) acc[i][j] = (f32x4){0.f, 0.f, 0.f, 0.f};

  #pragma unroll
  for (int kc = 0; kc < 4; ++kc) {
    __syncthreads();
    #pragma unroll
    for (int it = 0; it < 4; ++it) {
      int c = it * 256 + tid;           // 0..1023 16B-chunks
      int row = c >> 3;
      int col = ((c & 7) ^ (row & 7)) * 8;   // inverse-swizzled global column
      gload_lds16(eb + (size_t)(kbase + row) * DIM + kc * 64 + col, &Es[c * 8]);
      gload_lds16(xb + (size_t)(nbase + row) * DIM + kc * 64 + col, &Xs[c * 8]);
    }
    __syncthreads();  // drains vmcnt(0): staged data visible
    #pragma unroll
    for (int kk = 0; kk < 2; ++kk) {
      const int pd = (kk * 32 + lhi * 8) ^ ((l15 & 7) << 3);  // swizzled read
      bf16x8 af[4], bfv[4];
      #pragma unroll
      for (int am = 0; am < 4; ++am)
        af[am] = *(const bf16x8*)(&Es[(64 * wr + 16 * am + l15) * 64 + pd]);
      #pragma unroll
      for (int bn = 0; bn < 4; ++bn)
        bfv[bn] = *(const bf16x8*)(&Xs[(64 * wc + 16 * bn + l15) * 64 + pd]);
      #pragma unroll
      for (int am = 0; am < 4; ++am)
        #pragma unroll
        for (int bn = 0; bn < 4; ++bn)
          acc[am][bn] = __builtin_amdgcn_mfma_f32_16x16x32_bf16(
              af[am], bfv[bn], acc[am][bn], 0, 0, 0);
    }
  }

  // ---- epilogue: per output column, sorted top-3 key-triple over 128 codes --
  float bv[16];
  const int rb = 64 * wr + lhi * 4;    // block-local row base
  #pragma unroll
  for (int am = 0; am < 4; ++am)
    #pragma unroll
    for (int r = 0; r < 4; ++r) bv[am * 4 + r] = bks[rb + 16 * am + r];

  #pragma unroll
  for (int bn = 0; bn < 4; ++bn) {
    unsigned v1 = 0xFFFFFFFFu, v2 = 0xFFFFFFFFu, v3 = 0xFFFFFFFFu;
    #pragma unroll
    for (int am = 0; am < 4; ++am) {
      #pragma unroll
      for (int r = 0; r < 4; ++r) {
        float sc = fmaf(-2.f, acc[am][bn][r], bv[am * 4 + r]);
        unsigned key = (f2key(sc) & 0xFFFFFF80u) | (unsigned)(rb + 16 * am + r);
        unsigned t1 = umax2(v1, key); v1 = umin2(v1, key);
        unsigned t2 = umax2(v2, t1);  v2 = umin2(v2, t1);
        v3 = umin2(v3, t2);
      }
    }
    // merge sorted triples across the 4 lane-groups (xor 16, 32)
    #pragma unroll
    for (int mm = 16; mm <= 32; mm <<= 1) {
      unsigned o1 = (unsigned)__shfl_xor((int)v1, mm);
      unsigned o2 = (unsigned)__shfl_xor((int)v2, mm);
      unsigned o3 = (unsigned)__shfl_xor((int)v3, mm);
      unsigned z1 = umin2(v1, o1), w1 = umax2(v1, o1);
      unsigned z2 = umin2(v2, o2);
      unsigned z3 = umin2(v3, o3);
      v1 = z1;
      unsigned mx = umax2(w1, z2);
      v2 = umin2(w1, z2);
      v3 = umin2(mx, z3);
    }
    if (lane < 16) {
      int col = 64 * wc + 16 * bn + lane;
      t2lds[col][wr] = make_uint4(v1, v2, v3, 0u);
    }
  }
  __syncthreads();
  if (tid < 128) {
    uint4 a = t2lds[tid][0];
    uint4 b = t2lds[tid][1];
    unsigned z1 = umin2(a.x, b.x), w1 = umax2(a.x, b.x);
    unsigned z2 = umin2(a.y, b.y);
    unsigned z3 = umin2(a.z, b.z);
    unsigned mx = umax2(w1, z2);
    top2out[(size_t)kb * NTOK + nbase + tid] =
        make_uint4(z1, umin2(w1, z2), umin2(mx, z3), 0u);
  }
}

// ---------------- refine2: candidate-parallel np-faithful argmin -------------
// Candidate set per row: {i1,i2 of blocks with v<=lim} + full scan of blocks
// with v3<=lim (provably complete). One lane per candidate dot (fp64, exact);
// dd via the bit-validated np fp32 pipeline; (dd,k) lex-min = np first-min.
__global__ __launch_bounds__(256) void refine2(
    const uint4* __restrict__ top2,
    const float* __restrict__ x,
    const float* __restrict__ e,
    const float* __restrict__ An,
    const float* __restrict__ Bk,
    float* __restrict__ out,
    double* __restrict__ partials) {
  __shared__ float4 xs[4][64];
  __shared__ int cand[4][128];
  __shared__ int fblk[4][64];
  __shared__ double wsum[4];

  const int tid = threadIdx.x;
  const int lane = tid & 63, wid = tid >> 6;
  const int n = blockIdx.x * 4 + wid;   // one wave per row

  float4 xv = ((const float4*)x)[(size_t)n * 64 + lane];
  xs[wid][lane] = xv;

  uint4 t = top2[(size_t)lane * NTOK + n];   // lane = kblock id
  float fv1 = key2f(t.x), fv2 = key2f(t.y), fv3 = key2f(t.z);
  float m = fv1;
  #pragma unroll
  for (int s = 1; s < 64; s <<= 1) m = fminf(m, __shfl_xor(m, s));
  float lim = m + EPSM;

  unsigned long long b1 = __ballot(fv1 <= lim);
  unsigned long long b2 = __ballot(fv2 <= lim);
  unsigned long long b3 = __ballot(fv3 <= lim);
  unsigned long long ltm = (1ull << lane) - 1ull;
  int c1 = __popcll(b1);
  int ncand = c1 + __popcll(b2);
  if (fv1 <= lim) cand[wid][__popcll(b1 & ltm)] = lane * 128 + (int)(t.x & 127u);
  if (fv2 <= lim) cand[wid][c1 + __popcll(b2 & ltm)] = lane * 128 + (int)(t.y & 127u);
  int nflag = __popcll(b3);
  if (fv3 <= lim) fblk[wid][__popcll(b3 & ltm)] = lane;
  const float A0 = An[n];
  __syncthreads();

  float bd = INFINITY; int bi = 0x7FFFFFFF;
  for (int base = 0; base < ncand; base += 64) {
    int ci = base + lane;
    if (ci < ncand) {
      int k = cand[wid][ci];
      const float4* er = (const float4*)e + (size_t)k * 64;
      double d = 0.0;
      #pragma unroll 8
      for (int j = 0; j < 64; ++j) {
        float4 ev = er[j];
        float4 xf = xs[wid][j];
        d += (double)ev.x * (double)xf.x + (double)ev.y * (double)xf.y
           + (double)ev.z * (double)xf.z + (double)ev.w * (double)xf.w;
      }
      float dd = __fsub_rn(__fadd_rn(A0, Bk[k]), __fmul_rn(2.0f, (float)d));
      if (dd < bd || (dd == bd && k < bi)) { bd = dd; bi = k; }
    }
  }
  // rare exact fallback: blocks whose top-2 is provably insufficient
  for (int f = 0; f < nflag; ++f) {
    int b = fblk[wid][f];
    #pragma unroll
    for (int half = 0; half < 2; ++half) {
      int k = b * 128 + half * 64 + lane;   // all 64 lanes active
      const float4* er = (const float4*)e + (size_t)k * 64;
      double d = 0.0;
      #pragma unroll 4
      for (int j = 0; j < 64; ++j) {
        float4 ev = er[j];
        float4 xf = xs[wid][j];
        d += (double)ev.x * (double)xf.x + (double)ev.y * (double)xf.y
           + (double)ev.z * (double)xf.z + (double)ev.w * (double)xf.w;
      }
      float dd = __fsub_rn(__fadd_rn(A0, Bk[k]), __fmul_rn(2.0f, (float)d));
      if (dd < bd || (dd == bd && k < bi)) { bd = dd; bi = k; }
    }
  }
  // (dd, k) lexicographic min across the wave == numpy first-min
  #pragma unroll
  for (int s = 1; s < 64; s <<= 1) {
    float od = __shfl_xor(bd, s);
    int oi = __shfl_xor(bi, s);
    if (od < bd || (od == bd && oi < bi)) { bd = od; bi = oi; }
  }

  // outputs
  float4 q = ((const float4*)e)[(size_t)bi * 64 + lane];
  ((float4*)out)[(size_t)n * 64 + lane] = q;   // quantized_st == quantized
  double a0 = (double)q.x - (double)xv.x;
  double a1 = (double)q.y - (double)xv.y;
  double a2 = (double)q.z - (double)xv.z;
  double a3 = (double)q.w - (double)xv.w;
  double l = a0 * a0 + a1 * a1 + a2 * a2 + a3 * a3;
  #pragma unroll
  for (int sh = 1; sh < 64; sh <<= 1) l += __shfl_xor(l, sh);
  if (lane == 0) {
    wsum[wid] = l;
    out[(size_t)NTOK * DIM + 1 + n] = (float)bi;   // indices region
  }
  __syncthreads();
  if (tid == 0) partials[blockIdx.x] = wsum[0] + wsum[1] + wsum[2] + wsum[3];
}

// ---------------- finalize: deterministic loss reduction ----------------
__global__ __launch_bounds__(256) void finalize(const double* __restrict__ partials,
                                                float* __restrict__ out) {
  __shared__ double sd[256];
  double s = 0;
  for (int i = threadIdx.x; i < NTOK / 4; i += 256) s += partials[i];
  sd[threadIdx.x] = s;
  __syncthreads();
  for (int st = 128; st > 0; st >>= 1) {
    if (threadIdx.x < st) sd[threadIdx.x] += sd[threadIdx.x + st];
    __syncthreads();
  }
  if (threadIdx.x == 0)
    out[(size_t)NTOK * DIM] = (float)(1.25 * sd[0] / ((double)NTOK * (double)DIM));
}

extern "C" void kernel_launch(void* const* d_in, const int* in_sizes, int n_in,
                              void* d_out, int out_size, void* d_ws, size_t ws_size,
                              hipStream_t stream) {
  const float* x = (const float*)d_in[0];   // [32768, 256]
  const float* e = (const float*)d_in[1];   // [8192, 256]
  float* out = (float*)d_out;

  // workspace layout (~54.7 MB)
  char* w = (char*)d_ws;
  unsigned short* xb = (unsigned short*)(w + 0);            // 16,777,216 B
  unsigned short* eb = (unsigned short*)(w + 16777216);     //  4,194,304 B
  float* An        = (float*)(w + 20971520);                //    131,072 B
  float* Bk        = (float*)(w + 21102592);                //     32,768 B
  uint4* top2      = (uint4*)(w + 21135360);                // 33,554,432 B
  double* partials = (double*)(w + 54689792);               //     65,536 B

  cast_bf16_k<<<(NTOK * DIM / 8 + 255) / 256, 256, 0, stream>>>(x, xb, NTOK * DIM / 8);
  cast_bf16_k<<<(KEMB * DIM / 8 + 255) / 256, 256, 0, stream>>>(e, eb, KEMB * DIM / 8);
  rowsq_np<<<NTOK / 16, 256, 0, stream>>>(x, An, NTOK);
  rowsq_np<<<KEMB / 16, 256, 0, stream>>>(e, Bk, KEMB);

  score_top2<<<16384, 256, 0, stream>>>(eb, xb, Bk, top2);

  refine2<<<NTOK / 4, 256, 0, stream>>>(top2, x, e, An, Bk, out, partials);
  finalize<<<1, 256, 0, stream>>>(partials, out);
}

// Round 12
// 321.164 us; speedup vs baseline: 107.3082x; 1.1101x over previous
//
#include <hip/hip_runtime.h>
#include <hip/hip_bf16.h>

#define NTOK 32768   // input rows
#define KEMB 8192    // embedding codes
#define DIM  256     // feature dim
#define EPSM 1e-3f   // gate margin: worst-case |s_hat - np_dd| ~1.8e-4 incl key trunc

typedef __attribute__((ext_vector_type(8))) short bf16x8;
typedef __attribute__((ext_vector_type(4))) float f32x4;
typedef __attribute__((ext_vector_type(8))) unsigned short ushort8;

typedef __attribute__((address_space(3))) void as3_void;
typedef __attribute__((address_space(1))) const void as1_cvoid;

__device__ __forceinline__ void gload_lds16(const void* g, void* l) {
  __builtin_amdgcn_global_load_lds((as1_cvoid*)g, (as3_void*)l, 16, 0, 0);
}

__device__ __forceinline__ unsigned short f2bf(float f) {
  unsigned int u = __float_as_uint(f);
  unsigned int r = (u + 0x7FFFu + ((u >> 16) & 1u)) >> 16;
  return (unsigned short)r;
}

__device__ __forceinline__ unsigned umin2(unsigned a, unsigned b) { return a < b ? a : b; }
__device__ __forceinline__ unsigned umax2(unsigned a, unsigned b) { return a > b ? a : b; }

// biased-key scheme: all scores stored as (score + 1.0) > 0, so the raw fp32
// bit pattern is order-preserving. Low 7 bits carry the block-local index.
__device__ __forceinline__ float key2f(unsigned k) {
  return __uint_as_float(k & 0xFFFFFF80u) - 1.0f;
}

// ---------------- prep: fp32 -> bf16 copies ----------------
__global__ __launch_bounds__(256) void cast_bf16_k(const float* __restrict__ src,
                                                   unsigned short* __restrict__ dst,
                                                   int n8) {
  int i = blockIdx.x * 256 + threadIdx.x;
  if (i >= n8) return;
  const float4* s4 = (const float4*)src;
  float4 a = s4[2 * i], b = s4[2 * i + 1];
  ushort8 r;
  r[0] = f2bf(a.x); r[1] = f2bf(a.y); r[2] = f2bf(a.z); r[3] = f2bf(a.w);
  r[4] = f2bf(b.x); r[5] = f2bf(b.y); r[6] = f2bf(b.z); r[7] = f2bf(b.w);
  ((ushort8*)dst)[i] = r;
}

// ---------------- numpy-pairwise fp32 row sum of squares (validated r8) ------
__global__ __launch_bounds__(256) void rowsq_np(const float* __restrict__ src,
                                                float* __restrict__ dst,
                                                int nrows) {
  int g = (blockIdx.x * 256 + threadIdx.x) >> 4;   // row id
  if (g >= nrows) return;
  int l = threadIdx.x & 15;
  int j = l & 7, half = l >> 3;
  const float* row = src + (size_t)g * DIM + half * 128 + j;
  float s = 0.f;
  #pragma unroll
  for (int i = 0; i < 16; ++i) {
    float v = row[8 * i];
    s = __fadd_rn(s, __fmul_rn(v, v));
  }
  s = __fadd_rn(s, __shfl_xor(s, 1));
  s = __fadd_rn(s, __shfl_xor(s, 2));
  s = __fadd_rn(s, __shfl_xor(s, 4));
  s = __fadd_rn(s, __shfl_xor(s, 8));
  if (l == 0) dst[g] = s;
}

// ---------------- main: bf16 MFMA approx scores + per-block top-3 keys -------
// Transposed GEMM: C[k_local, n_local] = sum_d E[k,d] * X[n,d];
// biased score = (1+Bk[k]) - 2*C. Tile 128(k) x 256(n); 4 waves, each owns
// a 128x64 sub-tile (acc 8x4) -> 0.375 fragment-reads/MFMA and every output
// column's 128 codes live in one wave (no cross-wave merge, one barrier/chunk).
// LDS XOR-swizzle (T2, rule #21): linear global_load_lds dest + inverse-
// swizzled GLOBAL source + swizzled ds_read.
__global__ __launch_bounds__(256, 2) void score_top2(
    const unsigned short* __restrict__ eb,
    const unsigned short* __restrict__ xb,
    const float* __restrict__ Bk,
    uint4* __restrict__ top2out) {
  __shared__ __align__(16) short Es[128 * 64];
  __shared__ __align__(16) short Xs[256 * 64];
  __shared__ float bks[128];

  const int tid = threadIdx.x;
  // XCD-chunked decode: each XCD owns 16 contiguous 256-col n-panels
  const int bid = blockIdx.x;
  const int xcd = bid & 7;
  const int u = bid >> 3;
  const int nb = xcd * 16 + (u & 15);
  const int kb = u >> 4;
  const int kbase = kb * 128, nbase = nb * 256;
  const int lane = tid & 63;
  const int wid = tid >> 6;
  const int l15 = lane & 15, lhi = lane >> 4;

  if (tid < 128) bks[tid] = Bk[kbase + tid] + 1.0f;   // bias folded here

  f32x4 acc[8][4];
  #pragma unroll
  for (int i = 0; i < 8; ++i)
    #pragma unroll
    for (int j = 0; j < 4; ++j) acc[i][j] = (f32x4){0.f, 0.f, 0.f, 0.f};

  #pragma unroll
  for (int kc = 0; kc < 4; ++kc) {
    __syncthreads();  // previous chunk's frag reads done
    #pragma unroll
    for (int it = 0; it < 4; ++it) {
      int c = it * 256 + tid;                  // E chunks 0..1023
      int row = c >> 3;
      int col = ((c & 7) ^ (row & 7)) * 8;     // inverse-swizzled global column
      gload_lds16(eb + (size_t)(kbase + row) * DIM + kc * 64 + col, &Es[c * 8]);
    }
    #pragma unroll
    for (int it = 0; it < 8; ++it) {
      int c = it * 256 + tid;                  // X chunks 0..2047
      int row = c >> 3;
      int col = ((c & 7) ^ (row & 7)) * 8;
      gload_lds16(xb + (size_t)(nbase + row) * DIM + kc * 64 + col, &Xs[c * 8]);
    }
    __syncthreads();  // drains vmcnt(0): staged data visible
    #pragma unroll
    for (int kk = 0; kk < 2; ++kk) {
      const int pd = (kk * 32 + lhi * 8) ^ ((l15 & 7) << 3);  // swizzled read
      bf16x8 af[8], bfv[4];
      #pragma unroll
      for (int am = 0; am < 8; ++am)
        af[am] = *(const bf16x8*)(&Es[(16 * am + l15) * 64 + pd]);
      #pragma unroll
      for (int bn = 0; bn < 4; ++bn)
        bfv[bn] = *(const bf16x8*)(&Xs[(64 * wid + 16 * bn + l15) * 64 + pd]);
      #pragma unroll
      for (int am = 0; am < 8; ++am)
        #pragma unroll
        for (int bn = 0; bn < 4; ++bn)
          acc[am][bn] = __builtin_amdgcn_mfma_f32_16x16x32_bf16(
              af[am], bfv[bn], acc[am][bn], 0, 0, 0);
    }
  }

  // ---- epilogue: per column, sorted top-3 biased-key triple over 128 codes --
  const int rb = lhi * 4;                      // block-local row base (0..12)
  float bv[32];
  #pragma unroll
  for (int a = 0; a < 8; ++a)
    #pragma unroll
    for (int r = 0; r < 4; ++r) bv[a * 4 + r] = bks[16 * a + rb + r];

  #pragma unroll
  for (int bn = 0; bn < 4; ++bn) {
    unsigned v1 = 0xFFFFFFFFu, v2 = 0xFFFFFFFFu, v3 = 0xFFFFFFFFu;
    #pragma unroll
    for (int a = 0; a < 8; ++a) {
      #pragma unroll
      for (int r = 0; r < 4; ++r) {
        float sc = fmaf(-2.f, acc[a][bn][r], bv[a * 4 + r]);   // positive, monotone bits
        unsigned key = (__float_as_uint(sc) & 0xFFFFFF80u)
                     | (unsigned)(16 * a + rb + r);
        unsigned t1 = umax2(v1, key); v1 = umin2(v1, key);
        unsigned t2 = umax2(v2, t1);  v2 = umin2(v2, t1);
        v3 = umin2(v3, t2);
      }
    }
    // merge sorted triples across the 4 lane-groups (xor 16, 32)
    #pragma unroll
    for (int mm = 16; mm <= 32; mm <<= 1) {
      unsigned o1 = (unsigned)__shfl_xor((int)v1, mm);
      unsigned o2 = (unsigned)__shfl_xor((int)v2, mm);
      unsigned o3 = (unsigned)__shfl_xor((int)v3, mm);
      unsigned z1 = umin2(v1, o1), w1 = umax2(v1, o1);
      unsigned z2 = umin2(v2, o2);
      unsigned z3 = umin2(v3, o3);
      v1 = z1;
      unsigned mx = umax2(w1, z2);
      v2 = umin2(w1, z2);
      v3 = umin2(mx, z3);
    }
    if (lane < 16)
      top2out[(size_t)kb * NTOK + nbase + 64 * wid + 16 * bn + lane] =
          make_uint4(v1, v2, v3, 0u);
  }
}

// ---------------- refine2: candidate-parallel np-faithful argmin -------------
// Candidate set per row: {i1,i2 of blocks with v<=lim} + full scan of blocks
// with v3<=lim (provably complete). One lane per candidate dot (fp64, exact);
// dd via the bit-validated np fp32 pipeline; (dd,k) lex-min = np first-min.
__global__ __launch_bounds__(256) void refine2(
    const uint4* __restrict__ top2,
    const float* __restrict__ x,
    const float* __restrict__ e,
    const float* __restrict__ An,
    const float* __restrict__ Bk,
    float* __restrict__ out,
    double* __restrict__ partials) {
  __shared__ float4 xs[4][64];
  __shared__ int cand[4][128];
  __shared__ int fblk[4][64];
  __shared__ double wsum[4];

  const int tid = threadIdx.x;
  const int lane = tid & 63, wid = tid >> 6;
  const int n = blockIdx.x * 4 + wid;   // one wave per row

  float4 xv = ((const float4*)x)[(size_t)n * 64 + lane];
  xs[wid][lane] = xv;

  uint4 t = top2[(size_t)lane * NTOK + n];   // lane = kblock id
  float fv1 = key2f(t.x), fv2 = key2f(t.y), fv3 = key2f(t.z);
  float m = fv1;
  #pragma unroll
  for (int s = 1; s < 64; s <<= 1) m = fminf(m, __shfl_xor(m, s));
  float lim = m + EPSM;

  unsigned long long b1 = __ballot(fv1 <= lim);
  unsigned long long b2 = __ballot(fv2 <= lim);
  unsigned long long b3 = __ballot(fv3 <= lim);
  unsigned long long ltm = (1ull << lane) - 1ull;
  int c1 = __popcll(b1);
  int ncand = c1 + __popcll(b2);
  if (fv1 <= lim) cand[wid][__popcll(b1 & ltm)] = lane * 128 + (int)(t.x & 127u);
  if (fv2 <= lim) cand[wid][c1 + __popcll(b2 & ltm)] = lane * 128 + (int)(t.y & 127u);
  int nflag = __popcll(b3);
  if (fv3 <= lim) fblk[wid][__popcll(b3 & ltm)] = lane;
  const float A0 = An[n];
  __syncthreads();

  float bd = INFINITY; int bi = 0x7FFFFFFF;
  for (int base = 0; base < ncand; base += 64) {
    int ci = base + lane;
    if (ci < ncand) {
      int k = cand[wid][ci];
      const float4* er = (const float4*)e + (size_t)k * 64;
      double d = 0.0;
      #pragma unroll 8
      for (int j = 0; j < 64; ++j) {
        float4 ev = er[j];
        float4 xf = xs[wid][j];
        d += (double)ev.x * (double)xf.x + (double)ev.y * (double)xf.y
           + (double)ev.z * (double)xf.z + (double)ev.w * (double)xf.w;
      }
      float dd = __fsub_rn(__fadd_rn(A0, Bk[k]), __fmul_rn(2.0f, (float)d));
      if (dd < bd || (dd == bd && k < bi)) { bd = dd; bi = k; }
    }
  }
  // rare exact fallback: blocks whose top-2 is provably insufficient
  for (int f = 0; f < nflag; ++f) {
    int b = fblk[wid][f];
    #pragma unroll
    for (int half = 0; half < 2; ++half) {
      int k = b * 128 + half * 64 + lane;   // all 64 lanes active
      const float4* er = (const float4*)e + (size_t)k * 64;
      double d = 0.0;
      #pragma unroll 4
      for (int j = 0; j < 64; ++j) {
        float4 ev = er[j];
        float4 xf = xs[wid][j];
        d += (double)ev.x * (double)xf.x + (double)ev.y * (double)xf.y
           + (double)ev.z * (double)xf.z + (double)ev.w * (double)xf.w;
      }
      float dd = __fsub_rn(__fadd_rn(A0, Bk[k]), __fmul_rn(2.0f, (float)d));
      if (dd < bd || (dd == bd && k < bi)) { bd = dd; bi = k; }
    }
  }
  // (dd, k) lexicographic min across the wave == numpy first-min
  #pragma unroll
  for (int s = 1; s < 64; s <<= 1) {
    float od = __shfl_xor(bd, s);
    int oi = __shfl_xor(bi, s);
    if (od < bd || (od == bd && oi < bi)) { bd = od; bi = oi; }
  }

  // outputs
  float4 q = ((const float4*)e)[(size_t)bi * 64 + lane];
  ((float4*)out)[(size_t)n * 64 + lane] = q;   // quantized_st == quantized
  double a0 = (double)q.x - (double)xv.x;
  double a1 = (double)q.y - (double)xv.y;
  double a2 = (double)q.z - (double)xv.z;
  double a3 = (double)q.w - (double)xv.w;
  double l = a0 * a0 + a1 * a1 + a2 * a2 + a3 * a3;
  #pragma unroll
  for (int sh = 1; sh < 64; sh <<= 1) l += __shfl_xor(l, sh);
  if (lane == 0) {
    wsum[wid] = l;
    out[(size_t)NTOK * DIM + 1 + n] = (float)bi;   // indices region
  }
  __syncthreads();
  if (tid == 0) partials[blockIdx.x] = wsum[0] + wsum[1] + wsum[2] + wsum[3];
}

// ---------------- finalize: deterministic loss reduction ----------------
__global__ __launch_bounds__(256) void finalize(const double* __restrict__ partials,
                                                float* __restrict__ out) {
  __shared__ double sd[256];
  double s = 0;
  for (int i = threadIdx.x; i < NTOK / 4; i += 256) s += partials[i];
  sd[threadIdx.x] = s;
  __syncthreads();
  for (int st = 128; st > 0; st >>= 1) {
    if (threadIdx.x < st) sd[threadIdx.x] += sd[threadIdx.x + st];
    __syncthreads();
  }
  if (threadIdx.x == 0)
    out[(size_t)NTOK * DIM] = (float)(1.25 * sd[0] / ((double)NTOK * (double)DIM));
}

extern "C" void kernel_launch(void* const* d_in, const int* in_sizes, int n_in,
                              void* d_out, int out_size, void* d_ws, size_t ws_size,
                              hipStream_t stream) {
  const float* x = (const float*)d_in[0];   // [32768, 256]
  const float* e = (const float*)d_in[1];   // [8192, 256]
  float* out = (float*)d_out;

  // workspace layout (~54.7 MB)
  char* w = (char*)d_ws;
  unsigned short* xb = (unsigned short*)(w + 0);            // 16,777,216 B
  unsigned short* eb = (unsigned short*)(w + 16777216);     //  4,194,304 B
  float* An        = (float*)(w + 20971520);                //    131,072 B
  float* Bk        = (float*)(w + 21102592);                //     32,768 B
  uint4* top2      = (uint4*)(w + 21135360);                // 33,554,432 B
  double* partials = (double*)(w + 54689792);               //     65,536 B

  cast_bf16_k<<<(NTOK * DIM / 8 + 255) / 256, 256, 0, stream>>>(x, xb, NTOK * DIM / 8);
  cast_bf16_k<<<(KEMB * DIM / 8 + 255) / 256, 256, 0, stream>>>(e, eb, KEMB * DIM / 8);
  rowsq_np<<<NTOK / 16, 256, 0, stream>>>(x, An, NTOK);
  rowsq_np<<<KEMB / 16, 256, 0, stream>>>(e, Bk, KEMB);

  score_top2<<<8192, 256, 0, stream>>>(eb, xb, Bk, top2);

  refine2<<<NTOK / 4, 256, 0, stream>>>(top2, x, e, An, Bk, out, partials);
  finalize<<<1, 256, 0, stream>>>(partials, out);
}